// Round 5
// baseline (900.858 us; speedup 1.0000x reference)
//
#include <hip/hip_runtime.h>
#include <hip/hip_bf16.h>

#define N_NODES 100000
#define N_EDGES 1600000
#define N_GRAPHS 2000
#define D_IN 600
#define D_H 300
#define D_OUT 2

#define NPAD 320        // padded hidden width (multiple of 64)
#define K1PAD 640       // padded K for layer-1 GEMM
#define K2PAD 320       // padded K for layer-2 GEMM
#define MPAD 100096     // 782 * 128

typedef __bf16 bf16;
typedef __bf16 bf16x8 __attribute__((ext_vector_type(8)));
typedef float f32x4 __attribute__((ext_vector_type(4)));

__device__ __forceinline__ void gload16(const void* g, void* l) {
    __builtin_amdgcn_global_load_lds(
        (const __attribute__((address_space(1))) unsigned int*)g,
        (__attribute__((address_space(3))) unsigned int*)l, 16, 0, 0);
}

// ---------------- degree counting ----------------
__global__ __launch_bounds__(256) void count_deg(const int* __restrict__ src,
                                                 const int* __restrict__ dst,
                                                 int* __restrict__ deg_out,
                                                 int* __restrict__ deg_in) {
    int e = blockIdx.x * blockDim.x + threadIdx.x;
    if (e < N_EDGES) {
        atomicAdd(&deg_out[src[e]], 1);
        atomicAdd(&deg_in[dst[e]], 1);
    }
}

// ---------------- per-block sums of deg_in ----------------
__global__ __launch_bounds__(256) void block_sum(const int* __restrict__ deg_in,
                                                 int* __restrict__ bsum) {
    __shared__ int s[256];
    int i = blockIdx.x * 256 + threadIdx.x;
    s[threadIdx.x] = (i < N_NODES) ? deg_in[i] : 0;
    __syncthreads();
    for (int off = 128; off; off >>= 1) {
        if (threadIdx.x < off) s[threadIdx.x] += s[threadIdx.x + off];
        __syncthreads();
    }
    if (threadIdx.x == 0) bsum[blockIdx.x] = s[0];
}

// ---------------- serial scan over block sums (tiny) ----------------
__global__ void scan_serial(const int* __restrict__ bsum, int* __restrict__ boff, int nb) {
    if (threadIdx.x == 0 && blockIdx.x == 0) {
        int run = 0;
        for (int i = 0; i < nb; ++i) { boff[i] = run; run += bsum[i]; }
    }
}

// ---------------- per-node CSR offsets + inv-sqrt degrees ----------------
__global__ __launch_bounds__(256) void node_offsets(const int* __restrict__ deg_in,
                                                    const int* __restrict__ deg_out,
                                                    const int* __restrict__ boff,
                                                    int* __restrict__ row_start,
                                                    int* __restrict__ cursor,
                                                    float* __restrict__ inv_in,
                                                    float* __restrict__ inv_out) {
    __shared__ int s[256];
    int i = blockIdx.x * 256 + threadIdx.x;
    int d = (i < N_NODES) ? deg_in[i] : 0;
    s[threadIdx.x] = d;
    __syncthreads();
    for (int off = 1; off < 256; off <<= 1) {
        int v = 0;
        if (threadIdx.x >= off) v = s[threadIdx.x - off];
        __syncthreads();
        if (threadIdx.x >= off) s[threadIdx.x] += v;
        __syncthreads();
    }
    if (i < N_NODES) {
        int excl = s[threadIdx.x] - d;
        int rs = boff[blockIdx.x] + excl;
        row_start[i] = rs;
        cursor[i] = rs;
        int di = deg_in[i];
        int dout = deg_out[i];
        inv_in[i]  = (di   > 0) ? rsqrtf((float)di)   : 0.0f;
        inv_out[i] = (dout > 0) ? rsqrtf((float)dout) : 0.0f;
    }
}

// ---------------- fill CSR adjacency (incoming edges, store src) ----------------
__global__ __launch_bounds__(256) void fill_csr(const int* __restrict__ src,
                                                const int* __restrict__ dst,
                                                int* __restrict__ cursor,
                                                int* __restrict__ adj) {
    int e = blockIdx.x * blockDim.x + threadIdx.x;
    if (e < N_EDGES) {
        int pos = atomicAdd(&cursor[dst[e]], 1);
        adj[pos] = src[e];
    }
}

// ---------------- W [K][N] fp32 -> Bt [NPAD][Kpad] bf16 (transpose + zero pad) ----------------
__global__ __launch_bounds__(256) void conv_bt(const float* __restrict__ W, bf16* __restrict__ Bt,
                                               int K, int N, int Kpad) {
    int idx = blockIdx.x * 256 + threadIdx.x;
    int k = idx % Kpad;
    int n = idx / Kpad;
    if (n >= NPAD) return;
    bf16 v = (bf16)0.0f;
    if (k < K && n < N) v = (bf16)W[(size_t)k * N + n];
    Bt[(size_t)n * Kpad + k] = v;
}

// ---------------- pad bias / Wfc to NPAD with zeros ----------------
__global__ __launch_bounds__(256) void prep_small(const float* __restrict__ b1,
                                                  const float* __restrict__ b2,
                                                  const float* __restrict__ Wfc,
                                                  float* __restrict__ b1p,
                                                  float* __restrict__ b2p,
                                                  float* __restrict__ wfcp) {
    int i = blockIdx.x * 256 + threadIdx.x;
    if (i < NPAD) {
        b1p[i] = (i < D_H) ? b1[i] : 0.f;
        b2p[i] = (i < D_H) ? b2[i] : 0.f;
    }
    if (i < NPAD * 2) {
        wfcp[i] = (i < D_H * 2) ? Wfc[i] : 0.f;
    }
}

// ---------------- layer-1 MFMA GEMM with fused fp32->bf16 A staging ----------------
// A: fp32 x [N_NODES][600]; Bt: [NPAD][K1PAD] bf16; C = (A·Bt^T)*rowscale, bf16 [.][NPAD].
// 128x320 tile, 8 waves. A staged via reg: float4 x2 -> cvt -> ds_write_b128 (swizzled slot).
__global__ __launch_bounds__(512) void mfma_gemm_f32A(const float* __restrict__ A,
                                                      const bf16* __restrict__ Bt,
                                                      const float* __restrict__ rowscale,
                                                      bf16* __restrict__ C) {
    __shared__ bf16 As[128 * 64];   // 16 KB
    __shared__ bf16 Bs[320 * 64];   // 40 KB
    const int tid = threadIdx.x;
    const int lane = tid & 63;
    const int wid = tid >> 6;
    const int wr = wid >> 2;
    const int wc = wid & 3;
    const int blockRow = blockIdx.x * 128;
    const size_t rowBytesB = (size_t)K1PAD * 2;

    f32x4 acc[4][5] = {};

    const int nK = K1PAD >> 6;   // 10
    for (int t = 0; t < nK; ++t) {
        const size_t kByte = (size_t)t * 128;
        // A tile: load fp32, convert, write swizzled
#pragma unroll
        for (int c = 0; c < 2; ++c) {
            int o = c * 8192 + tid * 16;
            int row = o >> 7;          // 0..127
            int slot = (o >> 4) & 7;
            int gr = blockRow + row;
            int k = t * 64 + slot * 8;
            bf16x8 v = {};
            if (gr < N_NODES && k < D_IN) {
                const float* p = A + (size_t)gr * D_IN + k;
                float4 f0 = *(const float4*)p;
                float4 f1 = *(const float4*)(p + 4);
                v[0] = (bf16)f0.x; v[1] = (bf16)f0.y; v[2] = (bf16)f0.z; v[3] = (bf16)f0.w;
                v[4] = (bf16)f1.x; v[5] = (bf16)f1.y; v[6] = (bf16)f1.z; v[7] = (bf16)f1.w;
            }
            int waddr = row * 128 + ((slot ^ (row & 7)) << 4);
            *(bf16x8*)((char*)As + waddr) = v;
        }
        // B tile: 40 KB via global_load_lds with pre-swizzled source
#pragma unroll
        for (int c = 0; c < 5; ++c) {
            int o = c * 8192 + tid * 16;
            int row = o >> 7;
            int slot = (o >> 4) & 7;
            int srcs = slot ^ (row & 7);
            const char* g = (const char*)Bt + (size_t)row * rowBytesB + kByte + srcs * 16;
            gload16(g, (char*)Bs + o);
        }
        __syncthreads();
#pragma unroll
        for (int kk = 0; kk < 2; ++kk) {
            int slot = kk * 4 + (lane >> 4);
            bf16x8 af[4], bfr[5];
#pragma unroll
            for (int mi = 0; mi < 4; ++mi) {
                int row = wr * 64 + mi * 16 + (lane & 15);
                int addr = row * 128 + ((slot ^ (row & 7)) << 4);
                af[mi] = *(const bf16x8*)((const char*)As + addr);
            }
#pragma unroll
            for (int ni = 0; ni < 5; ++ni) {
                int row = wc * 80 + ni * 16 + (lane & 15);
                int addr = row * 128 + ((slot ^ (row & 7)) << 4);
                bfr[ni] = *(const bf16x8*)((const char*)Bs + addr);
            }
#pragma unroll
            for (int mi = 0; mi < 4; ++mi)
#pragma unroll
                for (int ni = 0; ni < 5; ++ni)
                    acc[mi][ni] = __builtin_amdgcn_mfma_f32_16x16x32_bf16(af[mi], bfr[ni], acc[mi][ni], 0, 0, 0);
        }
        __syncthreads();
    }
#pragma unroll
    for (int mi = 0; mi < 4; ++mi) {
#pragma unroll
        for (int i = 0; i < 4; ++i) {
            int gr = blockRow + wr * 64 + mi * 16 + ((lane >> 4) << 2) + i;
            if (gr >= N_NODES) continue;
            float sc = rowscale[gr];
#pragma unroll
            for (int ni = 0; ni < 5; ++ni) {
                int gc = wc * 80 + ni * 16 + (lane & 15);
                C[(size_t)gr * NPAD + gc] = (bf16)(acc[mi][ni][i] * sc);
            }
        }
    }
}

// ---------------- layer-2 MFMA GEMM (bf16 A via global_load_lds) ----------------
__global__ __launch_bounds__(512) void mfma_gemm(const bf16* __restrict__ A,
                                                 const bf16* __restrict__ Bt,
                                                 const float* __restrict__ rowscale,
                                                 bf16* __restrict__ C,
                                                 int M, int Kpad) {
    __shared__ bf16 As[128 * 64];
    __shared__ bf16 Bs[320 * 64];
    const int tid = threadIdx.x;
    const int lane = tid & 63;
    const int wid = tid >> 6;
    const int wr = wid >> 2;
    const int wc = wid & 3;
    const int blockRow = blockIdx.x * 128;
    const size_t rowBytes = (size_t)Kpad * 2;

    f32x4 acc[4][5] = {};

    const int nK = Kpad >> 6;
    for (int t = 0; t < nK; ++t) {
        const size_t kByte = (size_t)t * 128;
#pragma unroll
        for (int c = 0; c < 2; ++c) {
            int o = c * 8192 + tid * 16;
            int row = o >> 7;
            int slot = (o >> 4) & 7;
            int srcs = slot ^ (row & 7);
            const char* g = (const char*)A + (size_t)(blockRow + row) * rowBytes + kByte + srcs * 16;
            gload16(g, (char*)As + o);
        }
#pragma unroll
        for (int c = 0; c < 5; ++c) {
            int o = c * 8192 + tid * 16;
            int row = o >> 7;
            int slot = (o >> 4) & 7;
            int srcs = slot ^ (row & 7);
            const char* g = (const char*)Bt + (size_t)row * rowBytes + kByte + srcs * 16;
            gload16(g, (char*)Bs + o);
        }
        __syncthreads();
#pragma unroll
        for (int kk = 0; kk < 2; ++kk) {
            int slot = kk * 4 + (lane >> 4);
            bf16x8 af[4], bfr[5];
#pragma unroll
            for (int mi = 0; mi < 4; ++mi) {
                int row = wr * 64 + mi * 16 + (lane & 15);
                int addr = row * 128 + ((slot ^ (row & 7)) << 4);
                af[mi] = *(const bf16x8*)((const char*)As + addr);
            }
#pragma unroll
            for (int ni = 0; ni < 5; ++ni) {
                int row = wc * 80 + ni * 16 + (lane & 15);
                int addr = row * 128 + ((slot ^ (row & 7)) << 4);
                bfr[ni] = *(const bf16x8*)((const char*)Bs + addr);
            }
#pragma unroll
            for (int mi = 0; mi < 4; ++mi)
#pragma unroll
                for (int ni = 0; ni < 5; ++ni)
                    acc[mi][ni] = __builtin_amdgcn_mfma_f32_16x16x32_bf16(af[mi], bfr[ni], acc[mi][ni], 0, 0, 0);
        }
        __syncthreads();
    }
#pragma unroll
    for (int mi = 0; mi < 4; ++mi) {
#pragma unroll
        for (int i = 0; i < 4; ++i) {
            int gr = blockRow + wr * 64 + mi * 16 + ((lane >> 4) << 2) + i;
            if (gr >= M) continue;
            float sc = rowscale[gr];
#pragma unroll
            for (int ni = 0; ni < 5; ++ni) {
                int gc = wc * 80 + ni * 16 + (lane & 15);
                C[(size_t)gr * NPAD + gc] = (bf16)(acc[mi][ni][i] * sc);
            }
        }
    }
}

// ---------------- gather core: 16 B per edge at column c, unroll x8 ----------------
__device__ __forceinline__ void gather8(const bf16* __restrict__ m,
                                        const int* __restrict__ adj,
                                        int s, int d, int c, float acc[8]) {
    int e = 0;
    for (; e + 8 <= d; e += 8) {
        bf16x8 v0 = *(const bf16x8*)(m + (size_t)adj[s + e + 0] * NPAD + c);
        bf16x8 v1 = *(const bf16x8*)(m + (size_t)adj[s + e + 1] * NPAD + c);
        bf16x8 v2 = *(const bf16x8*)(m + (size_t)adj[s + e + 2] * NPAD + c);
        bf16x8 v3 = *(const bf16x8*)(m + (size_t)adj[s + e + 3] * NPAD + c);
        bf16x8 v4 = *(const bf16x8*)(m + (size_t)adj[s + e + 4] * NPAD + c);
        bf16x8 v5 = *(const bf16x8*)(m + (size_t)adj[s + e + 5] * NPAD + c);
        bf16x8 v6 = *(const bf16x8*)(m + (size_t)adj[s + e + 6] * NPAD + c);
        bf16x8 v7 = *(const bf16x8*)(m + (size_t)adj[s + e + 7] * NPAD + c);
#pragma unroll
        for (int q = 0; q < 8; ++q)
            acc[q] += ((float)v0[q] + (float)v1[q]) + ((float)v2[q] + (float)v3[q]) +
                      ((float)v4[q] + (float)v5[q]) + ((float)v6[q] + (float)v7[q]);
    }
    if (e + 4 <= d) {
        bf16x8 v0 = *(const bf16x8*)(m + (size_t)adj[s + e + 0] * NPAD + c);
        bf16x8 v1 = *(const bf16x8*)(m + (size_t)adj[s + e + 1] * NPAD + c);
        bf16x8 v2 = *(const bf16x8*)(m + (size_t)adj[s + e + 2] * NPAD + c);
        bf16x8 v3 = *(const bf16x8*)(m + (size_t)adj[s + e + 3] * NPAD + c);
#pragma unroll
        for (int q = 0; q < 8; ++q)
            acc[q] += ((float)v0[q] + (float)v1[q]) + ((float)v2[q] + (float)v3[q]);
        e += 4;
    }
    for (; e < d; ++e) {
        bf16x8 v = *(const bf16x8*)(m + (size_t)adj[s + e] * NPAD + c);
#pragma unroll
        for (int q = 0; q < 8; ++q) acc[q] += (float)v[q];
    }
}

// ---------------- layer-1 aggregation, flat mapping: thread -> (node, chunk) ----------------
// 320 threads/block = 8 nodes x 40 chunks; all lanes active.
__global__ __launch_bounds__(320) void aggregate_flat(const bf16* __restrict__ m,
                                                      const int* __restrict__ row_start,
                                                      const int* __restrict__ deg_in,
                                                      const int* __restrict__ adj,
                                                      const float* __restrict__ inv_in,
                                                      const float* __restrict__ biasp,
                                                      bf16* __restrict__ h) {
    int t = blockIdx.x * 320 + threadIdx.x;
    int node = t / 40;
    int chunk = t % 40;
    if (node >= N_NODES) return;
    int s = row_start[node];
    int d = deg_in[node];
    int c = chunk * 8;
    float acc[8] = {};
    gather8(m, adj, s, d, c, acc);
    float sc = inv_in[node];
    float4 bq0 = *(const float4*)(biasp + c);
    float4 bq1 = *(const float4*)(biasp + c + 4);
    float bv[8] = {bq0.x, bq0.y, bq0.z, bq0.w, bq1.x, bq1.y, bq1.z, bq1.w};
    bf16x8 o;
#pragma unroll
    for (int q = 0; q < 8; ++q) o[q] = (bf16)fmaxf(acc[q] * sc + bv[q], 0.f);
    *(bf16x8*)(h + (size_t)node * NPAD + c) = o;
}

// ---------------- fused layer-2 aggregation + fc + softmax + pooling, flat mapping ----------------
__global__ __launch_bounds__(320) void agg2_fc_pool(const bf16* __restrict__ m,
                                                    const int* __restrict__ row_start,
                                                    const int* __restrict__ deg_in,
                                                    const int* __restrict__ adj,
                                                    const float* __restrict__ inv_in,
                                                    const float* __restrict__ biasp,
                                                    const float* __restrict__ wfcp,
                                                    const float* __restrict__ bfc,
                                                    const int* __restrict__ gid,
                                                    float* __restrict__ pooled,
                                                    int* __restrict__ gcount) {
    __shared__ float red0[8], red1[8];
    int nl = threadIdx.x / 40;      // 0..7 local node
    int chunk = threadIdx.x % 40;
    int node = blockIdx.x * 8 + nl;
    if (threadIdx.x < 8) { red0[threadIdx.x] = 0.f; red1[threadIdx.x] = 0.f; }
    __syncthreads();
    float z0 = 0.f, z1 = 0.f;
    if (node < N_NODES) {
        int s = row_start[node];
        int d = deg_in[node];
        int c = chunk * 8;
        float acc[8] = {};
        gather8(m, adj, s, d, c, acc);
        float sc = inv_in[node];
        float4 bq0 = *(const float4*)(biasp + c);
        float4 bq1 = *(const float4*)(biasp + c + 4);
        float bv[8] = {bq0.x, bq0.y, bq0.z, bq0.w, bq1.x, bq1.y, bq1.z, bq1.w};
        float4 w0 = *(const float4*)(wfcp + c * 2);
        float4 w1 = *(const float4*)(wfcp + c * 2 + 4);
        float4 w2 = *(const float4*)(wfcp + c * 2 + 8);
        float4 w3 = *(const float4*)(wfcp + c * 2 + 12);
        float wz0[8] = {w0.x, w0.z, w1.x, w1.z, w2.x, w2.z, w3.x, w3.z};
        float wz1[8] = {w0.y, w0.w, w1.y, w1.w, w2.y, w2.w, w3.y, w3.w};
#pragma unroll
        for (int q = 0; q < 8; ++q) {
            float hq = fmaxf(acc[q] * sc + bv[q], 0.f);
            z0 += hq * wz0[q];
            z1 += hq * wz1[q];
        }
        atomicAdd(&red0[nl], z0);
        atomicAdd(&red1[nl], z1);
    }
    __syncthreads();
    if (chunk == 0 && node < N_NODES) {
        float s0 = red0[nl] + bfc[0], s1 = red1[nl] + bfc[1];
        float mx = fmaxf(s0, s1);
        float e0 = __expf(s0 - mx), e1 = __expf(s1 - mx);
        float inv = 1.f / (e0 + e1);
        int g = gid[node];
        atomicAdd(&pooled[g * 2 + 0], e0 * inv);
        atomicAdd(&pooled[g * 2 + 1], e1 * inv);
        atomicAdd(&gcount[g], 1);
    }
}

// ---------------- finalize: divide by counts ----------------
__global__ __launch_bounds__(256) void finalize(const float* __restrict__ pooled,
                                                const int* __restrict__ gcount,
                                                float* __restrict__ out) {
    int i = blockIdx.x * blockDim.x + threadIdx.x;
    if (i < N_GRAPHS * 2) {
        int g = i >> 1;
        float c = (float)max(gcount[g], 1);
        out[i] = pooled[i] / c;
    }
}

extern "C" void kernel_launch(void* const* d_in, const int* in_sizes, int n_in,
                              void* d_out, int out_size, void* d_ws, size_t ws_size,
                              hipStream_t stream) {
    const float* x   = (const float*)d_in[0];
    const float* W1  = (const float*)d_in[1];
    const float* b1  = (const float*)d_in[2];
    const float* W2  = (const float*)d_in[3];
    const float* b2  = (const float*)d_in[4];
    const float* Wfc = (const float*)d_in[5];
    const float* bfc = (const float*)d_in[6];
    const int* src   = (const int*)d_in[7];
    const int* dst   = (const int*)d_in[8];
    const int* gid   = (const int*)d_in[9];

    char* ws = (char*)d_ws;
    size_t off = 0;
    auto alloc = [&](size_t bytes) -> void* {
        void* p = ws + off;
        off = (off + bytes + 255) & ~(size_t)255;
        return p;
    };
    bf16* h_bf   = (bf16*)alloc((size_t)MPAD * NPAD * 2);      // 64.1 MB
    bf16* m_bf   = (bf16*)alloc((size_t)N_NODES * NPAD * 2);   // 64.0 MB
    bf16* B1t    = (bf16*)alloc((size_t)NPAD * K1PAD * 2);
    bf16* B2t    = (bf16*)alloc((size_t)NPAD * K2PAD * 2);
    int*   adj      = (int*)alloc((size_t)N_EDGES * 4);
    int*   row_st   = (int*)alloc((size_t)N_NODES * 4);
    int*   cursor   = (int*)alloc((size_t)N_NODES * 4);
    int*   deg_in   = (int*)alloc((size_t)N_NODES * 4);
    int*   deg_out  = (int*)alloc((size_t)N_NODES * 4);
    float* inv_in   = (float*)alloc((size_t)N_NODES * 4);
    float* inv_out  = (float*)alloc((size_t)N_NODES * 4);
    const int NB = (N_NODES + 255) / 256;
    int*   bsum     = (int*)alloc((size_t)NB * 4);
    int*   boff     = (int*)alloc((size_t)NB * 4);
    float* pooled   = (float*)alloc((size_t)N_GRAPHS * 2 * 4);
    int*   gcount   = (int*)alloc((size_t)N_GRAPHS * 4);
    float* b1p      = (float*)alloc((size_t)NPAD * 4);
    float* b2p      = (float*)alloc((size_t)NPAD * 4);
    float* wfcp     = (float*)alloc((size_t)NPAD * 2 * 4);

    hipMemsetAsync(deg_in, 0, (size_t)N_NODES * 4, stream);
    hipMemsetAsync(deg_out, 0, (size_t)N_NODES * 4, stream);
    hipMemsetAsync(pooled, 0, (size_t)N_GRAPHS * 2 * 4, stream);
    hipMemsetAsync(gcount, 0, (size_t)N_GRAPHS * 4, stream);

    // graph preprocessing
    count_deg<<<(N_EDGES + 255) / 256, 256, 0, stream>>>(src, dst, deg_out, deg_in);
    block_sum<<<NB, 256, 0, stream>>>(deg_in, bsum);
    scan_serial<<<1, 64, 0, stream>>>(bsum, boff, NB);
    node_offsets<<<NB, 256, 0, stream>>>(deg_in, deg_out, boff, row_st, cursor, inv_in, inv_out);
    fill_csr<<<(N_EDGES + 255) / 256, 256, 0, stream>>>(src, dst, cursor, adj);

    // weight conversions + padded small tensors
    conv_bt<<<(NPAD * K1PAD + 255) / 256, 256, 0, stream>>>(W1, B1t, D_IN, D_H, K1PAD);
    conv_bt<<<(NPAD * K2PAD + 255) / 256, 256, 0, stream>>>(W2, B2t, D_H, D_H, K2PAD);
    prep_small<<<3, 256, 0, stream>>>(b1, b2, Wfc, b1p, b2p, wfcp);

    // layer 1 (fused fp32->bf16 A staging)
    mfma_gemm_f32A<<<MPAD / 128, 512, 0, stream>>>(x, B1t, inv_out, m_bf);
    aggregate_flat<<<(N_NODES * 40 + 319) / 320, 320, 0, stream>>>(m_bf, row_st, deg_in, adj, inv_in, b1p, h_bf);
    // layer 2
    mfma_gemm<<<MPAD / 128, 512, 0, stream>>>(h_bf, B2t, inv_out, m_bf, N_NODES, K2PAD);
    // fused layer-2 aggregate + fc + softmax + pooling
    agg2_fc_pool<<<(N_NODES + 7) / 8, 320, 0, stream>>>(m_bf, row_st, deg_in, adj, inv_in, b2p,
                                                        wfcp, bfc, gid, pooled, gcount);
    finalize<<<(N_GRAPHS * 2 + 255) / 256, 256, 0, stream>>>(pooled, gcount, (float*)d_out);
}

// Round 6
// 705.861 us; speedup vs baseline: 1.2763x; 1.2763x over previous
//
#include <hip/hip_runtime.h>
#include <hip/hip_bf16.h>
#include <hip/hip_fp8.h>

#define N_NODES 100000
#define N_EDGES 1600000
#define N_GRAPHS 2000
#define D_IN 600
#define D_H 300
#define D_OUT 2

#define NPAD 320        // padded hidden width (multiple of 64)
#define K1PAD 640       // padded K for layer-1 GEMM
#define K2PAD 320       // padded K for layer-2 GEMM
#define MPAD 100096     // 782 * 128

typedef __bf16 bf16;
typedef __bf16 bf16x8 __attribute__((ext_vector_type(8)));
typedef float f32x4 __attribute__((ext_vector_type(4)));

__device__ __forceinline__ void gload16(const void* g, void* l) {
    __builtin_amdgcn_global_load_lds(
        (const __attribute__((address_space(1))) unsigned int*)g,
        (__attribute__((address_space(3))) unsigned int*)l, 16, 0, 0);
}

__device__ __forceinline__ float f8f(unsigned int b) {
    __hip_fp8_e4m3 t; t.__x = (__hip_fp8_storage_t)b; return (float)t;
}
__device__ __forceinline__ unsigned char ff8(float f) {
    __hip_fp8_e4m3 t(f); return (unsigned char)t.__x;
}

// ---------------- degree counting ----------------
__global__ __launch_bounds__(256) void count_deg(const int* __restrict__ src,
                                                 const int* __restrict__ dst,
                                                 int* __restrict__ deg_out,
                                                 int* __restrict__ deg_in) {
    int e = blockIdx.x * blockDim.x + threadIdx.x;
    if (e < N_EDGES) {
        atomicAdd(&deg_out[src[e]], 1);
        atomicAdd(&deg_in[dst[e]], 1);
    }
}

// ---------------- per-block sums of deg_in ----------------
__global__ __launch_bounds__(256) void block_sum(const int* __restrict__ deg_in,
                                                 int* __restrict__ bsum) {
    __shared__ int s[256];
    int i = blockIdx.x * 256 + threadIdx.x;
    s[threadIdx.x] = (i < N_NODES) ? deg_in[i] : 0;
    __syncthreads();
    for (int off = 128; off; off >>= 1) {
        if (threadIdx.x < off) s[threadIdx.x] += s[threadIdx.x + off];
        __syncthreads();
    }
    if (threadIdx.x == 0) bsum[blockIdx.x] = s[0];
}

// ---------------- serial scan over block sums (tiny) ----------------
__global__ void scan_serial(const int* __restrict__ bsum, int* __restrict__ boff, int nb) {
    if (threadIdx.x == 0 && blockIdx.x == 0) {
        int run = 0;
        for (int i = 0; i < nb; ++i) { boff[i] = run; run += bsum[i]; }
    }
}

// ---------------- per-node CSR offsets + inv-sqrt degrees ----------------
__global__ __launch_bounds__(256) void node_offsets(const int* __restrict__ deg_in,
                                                    const int* __restrict__ deg_out,
                                                    const int* __restrict__ boff,
                                                    int* __restrict__ row_start,
                                                    int* __restrict__ cursor,
                                                    float* __restrict__ inv_in,
                                                    float* __restrict__ inv_out) {
    __shared__ int s[256];
    int i = blockIdx.x * 256 + threadIdx.x;
    int d = (i < N_NODES) ? deg_in[i] : 0;
    s[threadIdx.x] = d;
    __syncthreads();
    for (int off = 1; off < 256; off <<= 1) {
        int v = 0;
        if (threadIdx.x >= off) v = s[threadIdx.x - off];
        __syncthreads();
        if (threadIdx.x >= off) s[threadIdx.x] += v;
        __syncthreads();
    }
    if (i < N_NODES) {
        int excl = s[threadIdx.x] - d;
        int rs = boff[blockIdx.x] + excl;
        row_start[i] = rs;
        cursor[i] = rs;
        int di = deg_in[i];
        int dout = deg_out[i];
        inv_in[i]  = (di   > 0) ? rsqrtf((float)di)   : 0.0f;
        inv_out[i] = (dout > 0) ? rsqrtf((float)dout) : 0.0f;
    }
}

// ---------------- fill CSR adjacency (incoming edges, store src) ----------------
__global__ __launch_bounds__(256) void fill_csr(const int* __restrict__ src,
                                                const int* __restrict__ dst,
                                                int* __restrict__ cursor,
                                                int* __restrict__ adj) {
    int e = blockIdx.x * blockDim.x + threadIdx.x;
    if (e < N_EDGES) {
        int pos = atomicAdd(&cursor[dst[e]], 1);
        adj[pos] = src[e];
    }
}

// ---------------- W [K][N] fp32 -> Bt [NPAD][Kpad] bf16 (transpose + zero pad) ----------------
__global__ __launch_bounds__(256) void conv_bt(const float* __restrict__ W, bf16* __restrict__ Bt,
                                               int K, int N, int Kpad) {
    int idx = blockIdx.x * 256 + threadIdx.x;
    int k = idx % Kpad;
    int n = idx / Kpad;
    if (n >= NPAD) return;
    bf16 v = (bf16)0.0f;
    if (k < K && n < N) v = (bf16)W[(size_t)k * N + n];
    Bt[(size_t)n * Kpad + k] = v;
}

// ---------------- pad bias / Wfc to NPAD with zeros ----------------
__global__ __launch_bounds__(256) void prep_small(const float* __restrict__ b1,
                                                  const float* __restrict__ b2,
                                                  const float* __restrict__ Wfc,
                                                  float* __restrict__ b1p,
                                                  float* __restrict__ b2p,
                                                  float* __restrict__ wfcp) {
    int i = blockIdx.x * 256 + threadIdx.x;
    if (i < NPAD) {
        b1p[i] = (i < D_H) ? b1[i] : 0.f;
        b2p[i] = (i < D_H) ? b2[i] : 0.f;
    }
    if (i < NPAD * 2) {
        wfcp[i] = (i < D_H * 2) ? Wfc[i] : 0.f;
    }
}

// ---------------- layer-1 MFMA GEMM with fused fp32->bf16 A staging, fp8 output ----------------
__global__ __launch_bounds__(512) void mfma_gemm_f32A(const float* __restrict__ A,
                                                      const bf16* __restrict__ Bt,
                                                      const float* __restrict__ rowscale,
                                                      unsigned char* __restrict__ C8) {
    __shared__ bf16 As[128 * 64];   // 16 KB
    __shared__ bf16 Bs[320 * 64];   // 40 KB
    const int tid = threadIdx.x;
    const int lane = tid & 63;
    const int wid = tid >> 6;
    const int wr = wid >> 2;
    const int wc = wid & 3;
    const int blockRow = blockIdx.x * 128;
    const size_t rowBytesB = (size_t)K1PAD * 2;

    f32x4 acc[4][5] = {};

    const int nK = K1PAD >> 6;   // 10
    for (int t = 0; t < nK; ++t) {
        const size_t kByte = (size_t)t * 128;
#pragma unroll
        for (int c = 0; c < 2; ++c) {
            int o = c * 8192 + tid * 16;
            int row = o >> 7;
            int slot = (o >> 4) & 7;
            int gr = blockRow + row;
            int k = t * 64 + slot * 8;
            bf16x8 v = {};
            if (gr < N_NODES && k < D_IN) {
                const float* p = A + (size_t)gr * D_IN + k;
                float4 f0 = *(const float4*)p;
                float4 f1 = *(const float4*)(p + 4);
                v[0] = (bf16)f0.x; v[1] = (bf16)f0.y; v[2] = (bf16)f0.z; v[3] = (bf16)f0.w;
                v[4] = (bf16)f1.x; v[5] = (bf16)f1.y; v[6] = (bf16)f1.z; v[7] = (bf16)f1.w;
            }
            int waddr = row * 128 + ((slot ^ (row & 7)) << 4);
            *(bf16x8*)((char*)As + waddr) = v;
        }
#pragma unroll
        for (int c = 0; c < 5; ++c) {
            int o = c * 8192 + tid * 16;
            int row = o >> 7;
            int slot = (o >> 4) & 7;
            int srcs = slot ^ (row & 7);
            const char* g = (const char*)Bt + (size_t)row * rowBytesB + kByte + srcs * 16;
            gload16(g, (char*)Bs + o);
        }
        __syncthreads();
#pragma unroll
        for (int kk = 0; kk < 2; ++kk) {
            int slot = kk * 4 + (lane >> 4);
            bf16x8 af[4], bfr[5];
#pragma unroll
            for (int mi = 0; mi < 4; ++mi) {
                int row = wr * 64 + mi * 16 + (lane & 15);
                int addr = row * 128 + ((slot ^ (row & 7)) << 4);
                af[mi] = *(const bf16x8*)((const char*)As + addr);
            }
#pragma unroll
            for (int ni = 0; ni < 5; ++ni) {
                int row = wc * 80 + ni * 16 + (lane & 15);
                int addr = row * 128 + ((slot ^ (row & 7)) << 4);
                bfr[ni] = *(const bf16x8*)((const char*)Bs + addr);
            }
#pragma unroll
            for (int mi = 0; mi < 4; ++mi)
#pragma unroll
                for (int ni = 0; ni < 5; ++ni)
                    acc[mi][ni] = __builtin_amdgcn_mfma_f32_16x16x32_bf16(af[mi], bfr[ni], acc[mi][ni], 0, 0, 0);
        }
        __syncthreads();
    }
#pragma unroll
    for (int mi = 0; mi < 4; ++mi) {
#pragma unroll
        for (int i = 0; i < 4; ++i) {
            int gr = blockRow + wr * 64 + mi * 16 + ((lane >> 4) << 2) + i;
            if (gr >= N_NODES) continue;
            float sc = rowscale[gr];
#pragma unroll
            for (int ni = 0; ni < 5; ++ni) {
                int gc = wc * 80 + ni * 16 + (lane & 15);
                C8[(size_t)gr * NPAD + gc] = ff8(acc[mi][ni][i] * sc);
            }
        }
    }
}

// ---------------- layer-2 MFMA GEMM (bf16 A via global_load_lds), fp8 output ----------------
__global__ __launch_bounds__(512) void mfma_gemm(const bf16* __restrict__ A,
                                                 const bf16* __restrict__ Bt,
                                                 const float* __restrict__ rowscale,
                                                 unsigned char* __restrict__ C8,
                                                 int M, int Kpad) {
    __shared__ bf16 As[128 * 64];
    __shared__ bf16 Bs[320 * 64];
    const int tid = threadIdx.x;
    const int lane = tid & 63;
    const int wid = tid >> 6;
    const int wr = wid >> 2;
    const int wc = wid & 3;
    const int blockRow = blockIdx.x * 128;
    const size_t rowBytes = (size_t)Kpad * 2;

    f32x4 acc[4][5] = {};

    const int nK = Kpad >> 6;
    for (int t = 0; t < nK; ++t) {
        const size_t kByte = (size_t)t * 128;
#pragma unroll
        for (int c = 0; c < 2; ++c) {
            int o = c * 8192 + tid * 16;
            int row = o >> 7;
            int slot = (o >> 4) & 7;
            int srcs = slot ^ (row & 7);
            const char* g = (const char*)A + (size_t)(blockRow + row) * rowBytes + kByte + srcs * 16;
            gload16(g, (char*)As + o);
        }
#pragma unroll
        for (int c = 0; c < 5; ++c) {
            int o = c * 8192 + tid * 16;
            int row = o >> 7;
            int slot = (o >> 4) & 7;
            int srcs = slot ^ (row & 7);
            const char* g = (const char*)Bt + (size_t)row * rowBytes + kByte + srcs * 16;
            gload16(g, (char*)Bs + o);
        }
        __syncthreads();
#pragma unroll
        for (int kk = 0; kk < 2; ++kk) {
            int slot = kk * 4 + (lane >> 4);
            bf16x8 af[4], bfr[5];
#pragma unroll
            for (int mi = 0; mi < 4; ++mi) {
                int row = wr * 64 + mi * 16 + (lane & 15);
                int addr = row * 128 + ((slot ^ (row & 7)) << 4);
                af[mi] = *(const bf16x8*)((const char*)As + addr);
            }
#pragma unroll
            for (int ni = 0; ni < 5; ++ni) {
                int row = wc * 80 + ni * 16 + (lane & 15);
                int addr = row * 128 + ((slot ^ (row & 7)) << 4);
                bfr[ni] = *(const bf16x8*)((const char*)Bs + addr);
            }
#pragma unroll
            for (int mi = 0; mi < 4; ++mi)
#pragma unroll
                for (int ni = 0; ni < 5; ++ni)
                    acc[mi][ni] = __builtin_amdgcn_mfma_f32_16x16x32_bf16(af[mi], bfr[ni], acc[mi][ni], 0, 0, 0);
        }
        __syncthreads();
    }
#pragma unroll
    for (int mi = 0; mi < 4; ++mi) {
#pragma unroll
        for (int i = 0; i < 4; ++i) {
            int gr = blockRow + wr * 64 + mi * 16 + ((lane >> 4) << 2) + i;
            if (gr >= M) continue;
            float sc = rowscale[gr];
#pragma unroll
            for (int ni = 0; ni < 5; ++ni) {
                int gc = wc * 80 + ni * 16 + (lane & 15);
                C8[(size_t)gr * NPAD + gc] = ff8(acc[mi][ni][i] * sc);
            }
        }
    }
}

// ---------------- fp8 gather core: wave-per-node, lane covers bytes lane*4..+3 and 256+lane ----
// Unrolled x4: 4 independent row gathers in flight. adj index is wave-uniform -> scalar loads.
__device__ __forceinline__ void gather_fp8(const unsigned char* __restrict__ m8,
                                           const int* __restrict__ adj,
                                           int s, int d, int lane, float acc[5]) {
    const int cb = lane * 4;
    const int c4 = 256 + lane;
    int e = 0;
    for (; e + 4 <= d; e += 4) {
        const unsigned char* r0 = m8 + (size_t)adj[s + e + 0] * NPAD;
        const unsigned char* r1 = m8 + (size_t)adj[s + e + 1] * NPAD;
        const unsigned char* r2 = m8 + (size_t)adj[s + e + 2] * NPAD;
        const unsigned char* r3 = m8 + (size_t)adj[s + e + 3] * NPAD;
        unsigned int u0 = *(const unsigned int*)(r0 + cb);
        unsigned int u1 = *(const unsigned int*)(r1 + cb);
        unsigned int u2 = *(const unsigned int*)(r2 + cb);
        unsigned int u3 = *(const unsigned int*)(r3 + cb);
        unsigned int b0 = r0[c4], b1 = r1[c4], b2 = r2[c4], b3 = r3[c4];
        acc[0] += (f8f(u0 & 0xff) + f8f(u1 & 0xff)) + (f8f(u2 & 0xff) + f8f(u3 & 0xff));
        acc[1] += (f8f((u0 >> 8) & 0xff) + f8f((u1 >> 8) & 0xff)) + (f8f((u2 >> 8) & 0xff) + f8f((u3 >> 8) & 0xff));
        acc[2] += (f8f((u0 >> 16) & 0xff) + f8f((u1 >> 16) & 0xff)) + (f8f((u2 >> 16) & 0xff) + f8f((u3 >> 16) & 0xff));
        acc[3] += (f8f(u0 >> 24) + f8f(u1 >> 24)) + (f8f(u2 >> 24) + f8f(u3 >> 24));
        acc[4] += (f8f(b0) + f8f(b1)) + (f8f(b2) + f8f(b3));
    }
    for (; e < d; ++e) {
        const unsigned char* r = m8 + (size_t)adj[s + e] * NPAD;
        unsigned int u = *(const unsigned int*)(r + cb);
        acc[0] += f8f(u & 0xff);
        acc[1] += f8f((u >> 8) & 0xff);
        acc[2] += f8f((u >> 16) & 0xff);
        acc[3] += f8f(u >> 24);
        acc[4] += f8f(r[c4]);
    }
}

// ---------------- layer-1 aggregation: h = relu(inv_in * sum m[adj] + bias), fp8 in / bf16 out --
__global__ __launch_bounds__(256) void aggregate_fp8(const unsigned char* __restrict__ m8,
                                                     const int* __restrict__ row_start,
                                                     const int* __restrict__ deg_in,
                                                     const int* __restrict__ adj,
                                                     const float* __restrict__ inv_in,
                                                     const float* __restrict__ biasp,
                                                     bf16* __restrict__ h) {
    int node = (int)((blockIdx.x * (size_t)blockDim.x + threadIdx.x) >> 6);
    int lane = threadIdx.x & 63;
    if (node >= N_NODES) return;
    int s = row_start[node];
    int d = deg_in[node];
    float acc[5] = {};
    gather_fp8(m8, adj, s, d, lane, acc);
    float sc = inv_in[node];
    int cA = lane * 4;
    int c4 = 256 + lane;
    float4 bq = *(const float4*)(biasp + cA);
    bf16* out = h + (size_t)node * NPAD;
    __bf16 o4[4];
    o4[0] = (bf16)fmaxf(acc[0] * sc + bq.x, 0.f);
    o4[1] = (bf16)fmaxf(acc[1] * sc + bq.y, 0.f);
    o4[2] = (bf16)fmaxf(acc[2] * sc + bq.z, 0.f);
    o4[3] = (bf16)fmaxf(acc[3] * sc + bq.w, 0.f);
    *(float2*)(out + cA) = *(float2*)o4;
    out[c4] = (bf16)fmaxf(acc[4] * sc + biasp[c4], 0.f);
}

// ---------------- fused layer-2 aggregation + fc + softmax + pooling (fp8 in) ----------------
__global__ __launch_bounds__(256) void agg2_fc_pool(const unsigned char* __restrict__ m8,
                                                    const int* __restrict__ row_start,
                                                    const int* __restrict__ deg_in,
                                                    const int* __restrict__ adj,
                                                    const float* __restrict__ inv_in,
                                                    const float* __restrict__ biasp,
                                                    const float* __restrict__ wfcp,
                                                    const float* __restrict__ bfc,
                                                    const int* __restrict__ gid,
                                                    float* __restrict__ pooled,
                                                    int* __restrict__ gcount) {
    int node = (int)((blockIdx.x * (size_t)blockDim.x + threadIdx.x) >> 6);
    int lane = threadIdx.x & 63;
    if (node >= N_NODES) return;
    int s = row_start[node];
    int d = deg_in[node];
    float acc[5] = {};
    gather_fp8(m8, adj, s, d, lane, acc);
    float sc = inv_in[node];
    int cA = lane * 4;
    int c4 = 256 + lane;
    float4 bq = *(const float4*)(biasp + cA);
    float h0 = fmaxf(acc[0] * sc + bq.x, 0.f);
    float h1 = fmaxf(acc[1] * sc + bq.y, 0.f);
    float h2 = fmaxf(acc[2] * sc + bq.z, 0.f);
    float h3 = fmaxf(acc[3] * sc + bq.w, 0.f);
    float h4 = fmaxf(acc[4] * sc + biasp[c4], 0.f);
    float4 wA0 = *(const float4*)(wfcp + cA * 2);
    float4 wA1 = *(const float4*)(wfcp + cA * 2 + 4);
    float z0 = h0 * wA0.x + h1 * wA0.z + h2 * wA1.x + h3 * wA1.z;
    float z1 = h0 * wA0.y + h1 * wA0.w + h2 * wA1.y + h3 * wA1.w;
    z0 += h4 * wfcp[c4 * 2];
    z1 += h4 * wfcp[c4 * 2 + 1];
    for (int off = 32; off; off >>= 1) {
        z0 += __shfl_down(z0, off);
        z1 += __shfl_down(z1, off);
    }
    if (lane == 0) {
        float s0 = z0 + bfc[0], s1 = z1 + bfc[1];
        float mx = fmaxf(s0, s1);
        float e0 = __expf(s0 - mx), e1 = __expf(s1 - mx);
        float inv = 1.f / (e0 + e1);
        int g = gid[node];
        atomicAdd(&pooled[g * 2 + 0], e0 * inv);
        atomicAdd(&pooled[g * 2 + 1], e1 * inv);
        atomicAdd(&gcount[g], 1);
    }
}

// ---------------- finalize: divide by counts ----------------
__global__ __launch_bounds__(256) void finalize(const float* __restrict__ pooled,
                                                const int* __restrict__ gcount,
                                                float* __restrict__ out) {
    int i = blockIdx.x * blockDim.x + threadIdx.x;
    if (i < N_GRAPHS * 2) {
        int g = i >> 1;
        float c = (float)max(gcount[g], 1);
        out[i] = pooled[i] / c;
    }
}

extern "C" void kernel_launch(void* const* d_in, const int* in_sizes, int n_in,
                              void* d_out, int out_size, void* d_ws, size_t ws_size,
                              hipStream_t stream) {
    const float* x   = (const float*)d_in[0];
    const float* W1  = (const float*)d_in[1];
    const float* b1  = (const float*)d_in[2];
    const float* W2  = (const float*)d_in[3];
    const float* b2  = (const float*)d_in[4];
    const float* Wfc = (const float*)d_in[5];
    const float* bfc = (const float*)d_in[6];
    const int* src   = (const int*)d_in[7];
    const int* dst   = (const int*)d_in[8];
    const int* gid   = (const int*)d_in[9];

    char* ws = (char*)d_ws;
    size_t off = 0;
    auto alloc = [&](size_t bytes) -> void* {
        void* p = ws + off;
        off = (off + bytes + 255) & ~(size_t)255;
        return p;
    };
    bf16* h_bf            = (bf16*)alloc((size_t)MPAD * NPAD * 2);        // 64.1 MB
    unsigned char* m8     = (unsigned char*)alloc((size_t)N_NODES * NPAD); // 32 MB
    bf16* B1t    = (bf16*)alloc((size_t)NPAD * K1PAD * 2);
    bf16* B2t    = (bf16*)alloc((size_t)NPAD * K2PAD * 2);
    int*   adj      = (int*)alloc((size_t)N_EDGES * 4);
    int*   row_st   = (int*)alloc((size_t)N_NODES * 4);
    int*   cursor   = (int*)alloc((size_t)N_NODES * 4);
    int*   deg_in   = (int*)alloc((size_t)N_NODES * 4);
    int*   deg_out  = (int*)alloc((size_t)N_NODES * 4);
    float* inv_in   = (float*)alloc((size_t)N_NODES * 4);
    float* inv_out  = (float*)alloc((size_t)N_NODES * 4);
    const int NB = (N_NODES + 255) / 256;
    int*   bsum     = (int*)alloc((size_t)NB * 4);
    int*   boff     = (int*)alloc((size_t)NB * 4);
    float* pooled   = (float*)alloc((size_t)N_GRAPHS * 2 * 4);
    int*   gcount   = (int*)alloc((size_t)N_GRAPHS * 4);
    float* b1p      = (float*)alloc((size_t)NPAD * 4);
    float* b2p      = (float*)alloc((size_t)NPAD * 4);
    float* wfcp     = (float*)alloc((size_t)NPAD * 2 * 4);

    hipMemsetAsync(deg_in, 0, (size_t)N_NODES * 4, stream);
    hipMemsetAsync(deg_out, 0, (size_t)N_NODES * 4, stream);
    hipMemsetAsync(pooled, 0, (size_t)N_GRAPHS * 2 * 4, stream);
    hipMemsetAsync(gcount, 0, (size_t)N_GRAPHS * 4, stream);

    // graph preprocessing
    count_deg<<<(N_EDGES + 255) / 256, 256, 0, stream>>>(src, dst, deg_out, deg_in);
    block_sum<<<NB, 256, 0, stream>>>(deg_in, bsum);
    scan_serial<<<1, 64, 0, stream>>>(bsum, boff, NB);
    node_offsets<<<NB, 256, 0, stream>>>(deg_in, deg_out, boff, row_st, cursor, inv_in, inv_out);
    fill_csr<<<(N_EDGES + 255) / 256, 256, 0, stream>>>(src, dst, cursor, adj);

    // weight conversions + padded small tensors
    conv_bt<<<(NPAD * K1PAD + 255) / 256, 256, 0, stream>>>(W1, B1t, D_IN, D_H, K1PAD);
    conv_bt<<<(NPAD * K2PAD + 255) / 256, 256, 0, stream>>>(W2, B2t, D_H, D_H, K2PAD);
    prep_small<<<3, 256, 0, stream>>>(b1, b2, Wfc, b1p, b2p, wfcp);

    // layer 1 (fused fp32->bf16 A staging, fp8 m output)
    mfma_gemm_f32A<<<MPAD / 128, 512, 0, stream>>>(x, B1t, inv_out, m8);
    aggregate_fp8<<<(N_NODES * 64 + 255) / 256, 256, 0, stream>>>(m8, row_st, deg_in, adj, inv_in, b1p, h_bf);
    // layer 2
    mfma_gemm<<<MPAD / 128, 512, 0, stream>>>(h_bf, B2t, inv_out, m8, N_NODES, K2PAD);
    // fused layer-2 aggregate + fc + softmax + pooling
    agg2_fc_pool<<<(N_NODES * 64 + 255) / 256, 256, 0, stream>>>(m8, row_st, deg_in, adj, inv_in, b2p,
                                                                 wfcp, bfc, gid, pooled, gcount);
    finalize<<<(N_GRAPHS * 2 + 255) / 256, 256, 0, stream>>>(pooled, gcount, (float*)d_out);
}

// Round 7
// 684.707 us; speedup vs baseline: 1.3157x; 1.0309x over previous
//
#include <hip/hip_runtime.h>
#include <hip/hip_bf16.h>
#include <hip/hip_fp8.h>

#define N_NODES 100000
#define N_EDGES 1600000
#define N_GRAPHS 2000
#define D_IN 600
#define D_H 300
#define D_OUT 2

#define NPAD 320        // padded hidden width (multiple of 64)
#define K1PAD 640       // padded K for layer-1 GEMM
#define K2PAD 320       // padded K for layer-2 GEMM
#define MPAD 100096     // 782 * 128

typedef __bf16 bf16;
typedef __bf16 bf16x8 __attribute__((ext_vector_type(8)));
typedef float f32x4 __attribute__((ext_vector_type(4)));

__device__ __forceinline__ float f8f(unsigned int b) {
    __hip_fp8_e4m3 t; t.__x = (__hip_fp8_storage_t)b; return (float)t;
}
__device__ __forceinline__ unsigned char ff8(float f) {
    __hip_fp8_e4m3 t(f); return (unsigned char)t.__x;
}

// ---------------- degree counting ----------------
__global__ __launch_bounds__(256) void count_deg(const int* __restrict__ src,
                                                 const int* __restrict__ dst,
                                                 int* __restrict__ deg_out,
                                                 int* __restrict__ deg_in) {
    int e = blockIdx.x * blockDim.x + threadIdx.x;
    if (e < N_EDGES) {
        atomicAdd(&deg_out[src[e]], 1);
        atomicAdd(&deg_in[dst[e]], 1);
    }
}

// ---------------- per-block sums of deg_in ----------------
__global__ __launch_bounds__(256) void block_sum(const int* __restrict__ deg_in,
                                                 int* __restrict__ bsum) {
    __shared__ int s[256];
    int i = blockIdx.x * 256 + threadIdx.x;
    s[threadIdx.x] = (i < N_NODES) ? deg_in[i] : 0;
    __syncthreads();
    for (int off = 128; off; off >>= 1) {
        if (threadIdx.x < off) s[threadIdx.x] += s[threadIdx.x + off];
        __syncthreads();
    }
    if (threadIdx.x == 0) bsum[blockIdx.x] = s[0];
}

// ---------------- serial scan over block sums (tiny) ----------------
__global__ void scan_serial(const int* __restrict__ bsum, int* __restrict__ boff, int nb) {
    if (threadIdx.x == 0 && blockIdx.x == 0) {
        int run = 0;
        for (int i = 0; i < nb; ++i) { boff[i] = run; run += bsum[i]; }
    }
}

// ---------------- per-node CSR offsets + inv-sqrt degrees ----------------
__global__ __launch_bounds__(256) void node_offsets(const int* __restrict__ deg_in,
                                                    const int* __restrict__ deg_out,
                                                    const int* __restrict__ boff,
                                                    int* __restrict__ row_start,
                                                    int* __restrict__ cursor,
                                                    float* __restrict__ inv_in,
                                                    float* __restrict__ inv_out) {
    __shared__ int s[256];
    int i = blockIdx.x * 256 + threadIdx.x;
    int d = (i < N_NODES) ? deg_in[i] : 0;
    s[threadIdx.x] = d;
    __syncthreads();
    for (int off = 1; off < 256; off <<= 1) {
        int v = 0;
        if (threadIdx.x >= off) v = s[threadIdx.x - off];
        __syncthreads();
        if (threadIdx.x >= off) s[threadIdx.x] += v;
        __syncthreads();
    }
    if (i < N_NODES) {
        int excl = s[threadIdx.x] - d;
        int rs = boff[blockIdx.x] + excl;
        row_start[i] = rs;
        cursor[i] = rs;
        int di = deg_in[i];
        int dout = deg_out[i];
        inv_in[i]  = (di   > 0) ? rsqrtf((float)di)   : 0.0f;
        inv_out[i] = (dout > 0) ? rsqrtf((float)dout) : 0.0f;
    }
}

// ---------------- fill CSR adjacency (incoming edges, store src) ----------------
__global__ __launch_bounds__(256) void fill_csr(const int* __restrict__ src,
                                                const int* __restrict__ dst,
                                                int* __restrict__ cursor,
                                                int* __restrict__ adj) {
    int e = blockIdx.x * blockDim.x + threadIdx.x;
    if (e < N_EDGES) {
        int pos = atomicAdd(&cursor[dst[e]], 1);
        adj[pos] = src[e];
    }
}

// ---------------- W [K][N] fp32 -> Bt [NPAD][Kpad] bf16 (transpose + zero pad) ----------------
__global__ __launch_bounds__(256) void conv_bt(const float* __restrict__ W, bf16* __restrict__ Bt,
                                               int K, int N, int Kpad) {
    int idx = blockIdx.x * 256 + threadIdx.x;
    int k = idx % Kpad;
    int n = idx / Kpad;
    if (n >= NPAD) return;
    bf16 v = (bf16)0.0f;
    if (k < K && n < N) v = (bf16)W[(size_t)k * N + n];
    Bt[(size_t)n * Kpad + k] = v;
}

// ---------------- pad bias / Wfc to NPAD with zeros ----------------
__global__ __launch_bounds__(256) void prep_small(const float* __restrict__ b1,
                                                  const float* __restrict__ b2,
                                                  const float* __restrict__ Wfc,
                                                  float* __restrict__ b1p,
                                                  float* __restrict__ b2p,
                                                  float* __restrict__ wfcp) {
    int i = blockIdx.x * 256 + threadIdx.x;
    if (i < NPAD) {
        b1p[i] = (i < D_H) ? b1[i] : 0.f;
        b2p[i] = (i < D_H) ? b2[i] : 0.f;
    }
    if (i < NPAD * 2) {
        wfcp[i] = (i < D_H * 2) ? Wfc[i] : 0.f;
    }
}

// ---------------- reg-staged MFMA GEMM (T14 async-STAGE), fp8 output ----------------
// C[r][n] = (sum_k A[r][k]*Bt[n][k]) * rowscale[r], tile 128x320, 8 waves.
// Staging: global->reg (issued one K-tile early, in flight under MFMA) -> ds_write.
// LDS image identical to prior kernel: pre-swizzled source, linear write, XOR-swizzled read.
template<int NK, bool AF32>
__global__ __launch_bounds__(512) void gemm_rs(const float* __restrict__ Af,
                                               const bf16* __restrict__ Ab,
                                               const bf16* __restrict__ Bt,
                                               const float* __restrict__ rowscale,
                                               unsigned char* __restrict__ C8,
                                               int M) {
    __shared__ bf16 As[128 * 64];   // 16 KB
    __shared__ bf16 Bs[320 * 64];   // 40 KB
    const int tid = threadIdx.x;
    const int lane = tid & 63;
    const int wid = tid >> 6;
    const int wr = wid >> 2;
    const int wc = wid & 3;
    const int blockRow = blockIdx.x * 128;
    const int Kpad = NK * 64;
    const size_t rowBytes = (size_t)Kpad * 2;

    f32x4 acc[4][5] = {};

    // staging geometry (per-thread, fixed): LDS offset o, row, swizzled source slot
    int aO[2], aRow[2], aKs[2];   // aKs = source k-element offset within 64-wide K tile
    #pragma unroll
    for (int c = 0; c < 2; ++c) {
        int o = c * 8192 + tid * 16;
        int row = o >> 7;
        int slot = (o >> 4) & 7;
        aO[c] = o; aRow[c] = row; aKs[c] = (slot ^ (row & 7)) * 8;
    }
    int bO[5], bRow[5], bKs[5];
    #pragma unroll
    for (int c = 0; c < 5; ++c) {
        int o = c * 8192 + tid * 16;
        int row = o >> 7;
        int slot = (o >> 4) & 7;
        bO[c] = o; bRow[c] = row; bKs[c] = (slot ^ (row & 7)) * 8;
    }

    float4 fA[2][2];   // f32-A staging regs
    bf16x8 sA[2];      // bf16-A staging regs
    bf16x8 sB[5];      // B staging regs

    auto loadTile = [&](int t) {
        #pragma unroll
        for (int c = 0; c < 2; ++c) {
            if (AF32) {
                int gr = blockRow + aRow[c];
                int k = t * 64 + aKs[c];
                if (gr < N_NODES && k < D_IN) {
                    const float* p = Af + (size_t)gr * D_IN + k;
                    fA[c][0] = *(const float4*)p;
                    fA[c][1] = *(const float4*)(p + 4);
                } else {
                    fA[c][0] = make_float4(0.f, 0.f, 0.f, 0.f);
                    fA[c][1] = make_float4(0.f, 0.f, 0.f, 0.f);
                }
            } else {
                const char* g = (const char*)Ab + (size_t)(blockRow + aRow[c]) * rowBytes
                                + (size_t)t * 128 + aKs[c] * 2;
                sA[c] = *(const bf16x8*)g;
            }
        }
        #pragma unroll
        for (int c = 0; c < 5; ++c) {
            const char* g = (const char*)Bt + (size_t)bRow[c] * rowBytes
                            + (size_t)t * 128 + bKs[c] * 2;
            sB[c] = *(const bf16x8*)g;
        }
    };

    loadTile(0);

    for (int t = 0; t < NK; ++t) {
        __syncthreads();   // prev tile's LDS reads done; drains this tile's loads
        // commit staged tile to LDS
        #pragma unroll
        for (int c = 0; c < 2; ++c) {
            bf16x8 v;
            if (AF32) {
                v[0] = (bf16)fA[c][0].x; v[1] = (bf16)fA[c][0].y;
                v[2] = (bf16)fA[c][0].z; v[3] = (bf16)fA[c][0].w;
                v[4] = (bf16)fA[c][1].x; v[5] = (bf16)fA[c][1].y;
                v[6] = (bf16)fA[c][1].z; v[7] = (bf16)fA[c][1].w;
            } else {
                v = sA[c];
            }
            *(bf16x8*)((char*)As + aO[c]) = v;
        }
        #pragma unroll
        for (int c = 0; c < 5; ++c)
            *(bf16x8*)((char*)Bs + bO[c]) = sB[c];
        __syncthreads();   // tile visible
        if (t + 1 < NK) loadTile(t + 1);   // in flight under MFMA phase
        // compute
        #pragma unroll
        for (int kk = 0; kk < 2; ++kk) {
            int slot = kk * 4 + (lane >> 4);
            bf16x8 af[4], bfr[5];
            #pragma unroll
            for (int mi = 0; mi < 4; ++mi) {
                int row = wr * 64 + mi * 16 + (lane & 15);
                int addr = row * 128 + ((slot ^ (row & 7)) << 4);
                af[mi] = *(const bf16x8*)((const char*)As + addr);
            }
            #pragma unroll
            for (int ni = 0; ni < 5; ++ni) {
                int row = wc * 80 + ni * 16 + (lane & 15);
                int addr = row * 128 + ((slot ^ (row & 7)) << 4);
                bfr[ni] = *(const bf16x8*)((const char*)Bs + addr);
            }
            #pragma unroll
            for (int mi = 0; mi < 4; ++mi)
                #pragma unroll
                for (int ni = 0; ni < 5; ++ni)
                    acc[mi][ni] = __builtin_amdgcn_mfma_f32_16x16x32_bf16(af[mi], bfr[ni], acc[mi][ni], 0, 0, 0);
        }
    }
    // epilogue
    #pragma unroll
    for (int mi = 0; mi < 4; ++mi) {
        #pragma unroll
        for (int i = 0; i < 4; ++i) {
            int gr = blockRow + wr * 64 + mi * 16 + ((lane >> 4) << 2) + i;
            if (gr >= M) continue;
            float sc = rowscale[gr];
            #pragma unroll
            for (int ni = 0; ni < 5; ++ni) {
                int gc = wc * 80 + ni * 16 + (lane & 15);
                C8[(size_t)gr * NPAD + gc] = ff8(acc[mi][ni][i] * sc);
            }
        }
    }
}

// ---------------- fp8 gather core: wave-per-node, lane covers bytes lane*4..+3 and 256+lane ----
__device__ __forceinline__ void gather_fp8(const unsigned char* __restrict__ m8,
                                           const int* __restrict__ adj,
                                           int s, int d, int lane, float acc[5]) {
    const int cb = lane * 4;
    const int c4 = 256 + lane;
    int e = 0;
    for (; e + 4 <= d; e += 4) {
        const unsigned char* r0 = m8 + (size_t)adj[s + e + 0] * NPAD;
        const unsigned char* r1 = m8 + (size_t)adj[s + e + 1] * NPAD;
        const unsigned char* r2 = m8 + (size_t)adj[s + e + 2] * NPAD;
        const unsigned char* r3 = m8 + (size_t)adj[s + e + 3] * NPAD;
        unsigned int u0 = *(const unsigned int*)(r0 + cb);
        unsigned int u1 = *(const unsigned int*)(r1 + cb);
        unsigned int u2 = *(const unsigned int*)(r2 + cb);
        unsigned int u3 = *(const unsigned int*)(r3 + cb);
        unsigned int b0 = r0[c4], b1 = r1[c4], b2 = r2[c4], b3 = r3[c4];
        acc[0] += (f8f(u0 & 0xff) + f8f(u1 & 0xff)) + (f8f(u2 & 0xff) + f8f(u3 & 0xff));
        acc[1] += (f8f((u0 >> 8) & 0xff) + f8f((u1 >> 8) & 0xff)) + (f8f((u2 >> 8) & 0xff) + f8f((u3 >> 8) & 0xff));
        acc[2] += (f8f((u0 >> 16) & 0xff) + f8f((u1 >> 16) & 0xff)) + (f8f((u2 >> 16) & 0xff) + f8f((u3 >> 16) & 0xff));
        acc[3] += (f8f(u0 >> 24) + f8f(u1 >> 24)) + (f8f(u2 >> 24) + f8f(u3 >> 24));
        acc[4] += (f8f(b0) + f8f(b1)) + (f8f(b2) + f8f(b3));
    }
    for (; e < d; ++e) {
        const unsigned char* r = m8 + (size_t)adj[s + e] * NPAD;
        unsigned int u = *(const unsigned int*)(r + cb);
        acc[0] += f8f(u & 0xff);
        acc[1] += f8f((u >> 8) & 0xff);
        acc[2] += f8f((u >> 16) & 0xff);
        acc[3] += f8f(u >> 24);
        acc[4] += f8f(r[c4]);
    }
}

// ---------------- layer-1 aggregation: h = relu(inv_in * sum m[adj] + bias), fp8 in / bf16 out --
__global__ __launch_bounds__(256) void aggregate_fp8(const unsigned char* __restrict__ m8,
                                                     const int* __restrict__ row_start,
                                                     const int* __restrict__ deg_in,
                                                     const int* __restrict__ adj,
                                                     const float* __restrict__ inv_in,
                                                     const float* __restrict__ biasp,
                                                     bf16* __restrict__ h) {
    int node = (int)((blockIdx.x * (size_t)blockDim.x + threadIdx.x) >> 6);
    int lane = threadIdx.x & 63;
    if (node >= N_NODES) return;
    int s = row_start[node];
    int d = deg_in[node];
    float acc[5] = {};
    gather_fp8(m8, adj, s, d, lane, acc);
    float sc = inv_in[node];
    int cA = lane * 4;
    int c4 = 256 + lane;
    float4 bq = *(const float4*)(biasp + cA);
    bf16* out = h + (size_t)node * NPAD;
    __bf16 o4[4];
    o4[0] = (bf16)fmaxf(acc[0] * sc + bq.x, 0.f);
    o4[1] = (bf16)fmaxf(acc[1] * sc + bq.y, 0.f);
    o4[2] = (bf16)fmaxf(acc[2] * sc + bq.z, 0.f);
    o4[3] = (bf16)fmaxf(acc[3] * sc + bq.w, 0.f);
    *(float2*)(out + cA) = *(float2*)o4;
    out[c4] = (bf16)fmaxf(acc[4] * sc + biasp[c4], 0.f);
}

// ---------------- fused layer-2 aggregation + fc + softmax + pooling (fp8 in) ----------------
__global__ __launch_bounds__(256) void agg2_fc_pool(const unsigned char* __restrict__ m8,
                                                    const int* __restrict__ row_start,
                                                    const int* __restrict__ deg_in,
                                                    const int* __restrict__ adj,
                                                    const float* __restrict__ inv_in,
                                                    const float* __restrict__ biasp,
                                                    const float* __restrict__ wfcp,
                                                    const float* __restrict__ bfc,
                                                    const int* __restrict__ gid,
                                                    float* __restrict__ pooled,
                                                    int* __restrict__ gcount) {
    int node = (int)((blockIdx.x * (size_t)blockDim.x + threadIdx.x) >> 6);
    int lane = threadIdx.x & 63;
    if (node >= N_NODES) return;
    int s = row_start[node];
    int d = deg_in[node];
    float acc[5] = {};
    gather_fp8(m8, adj, s, d, lane, acc);
    float sc = inv_in[node];
    int cA = lane * 4;
    int c4 = 256 + lane;
    float4 bq = *(const float4*)(biasp + cA);
    float h0 = fmaxf(acc[0] * sc + bq.x, 0.f);
    float h1 = fmaxf(acc[1] * sc + bq.y, 0.f);
    float h2 = fmaxf(acc[2] * sc + bq.z, 0.f);
    float h3 = fmaxf(acc[3] * sc + bq.w, 0.f);
    float h4 = fmaxf(acc[4] * sc + biasp[c4], 0.f);
    float4 wA0 = *(const float4*)(wfcp + cA * 2);
    float4 wA1 = *(const float4*)(wfcp + cA * 2 + 4);
    float z0 = h0 * wA0.x + h1 * wA0.z + h2 * wA1.x + h3 * wA1.z;
    float z1 = h0 * wA0.y + h1 * wA0.w + h2 * wA1.y + h3 * wA1.w;
    z0 += h4 * wfcp[c4 * 2];
    z1 += h4 * wfcp[c4 * 2 + 1];
    for (int off = 32; off; off >>= 1) {
        z0 += __shfl_down(z0, off);
        z1 += __shfl_down(z1, off);
    }
    if (lane == 0) {
        float s0 = z0 + bfc[0], s1 = z1 + bfc[1];
        float mx = fmaxf(s0, s1);
        float e0 = __expf(s0 - mx), e1 = __expf(s1 - mx);
        float inv = 1.f / (e0 + e1);
        int g = gid[node];
        atomicAdd(&pooled[g * 2 + 0], e0 * inv);
        atomicAdd(&pooled[g * 2 + 1], e1 * inv);
        atomicAdd(&gcount[g], 1);
    }
}

// ---------------- finalize: divide by counts ----------------
__global__ __launch_bounds__(256) void finalize(const float* __restrict__ pooled,
                                                const int* __restrict__ gcount,
                                                float* __restrict__ out) {
    int i = blockIdx.x * blockDim.x + threadIdx.x;
    if (i < N_GRAPHS * 2) {
        int g = i >> 1;
        float c = (float)max(gcount[g], 1);
        out[i] = pooled[i] / c;
    }
}

extern "C" void kernel_launch(void* const* d_in, const int* in_sizes, int n_in,
                              void* d_out, int out_size, void* d_ws, size_t ws_size,
                              hipStream_t stream) {
    const float* x   = (const float*)d_in[0];
    const float* W1  = (const float*)d_in[1];
    const float* b1  = (const float*)d_in[2];
    const float* W2  = (const float*)d_in[3];
    const float* b2  = (const float*)d_in[4];
    const float* Wfc = (const float*)d_in[5];
    const float* bfc = (const float*)d_in[6];
    const int* src   = (const int*)d_in[7];
    const int* dst   = (const int*)d_in[8];
    const int* gid   = (const int*)d_in[9];

    char* ws = (char*)d_ws;
    size_t off = 0;
    auto alloc = [&](size_t bytes) -> void* {
        void* p = ws + off;
        off = (off + bytes + 255) & ~(size_t)255;
        return p;
    };
    bf16* h_bf            = (bf16*)alloc((size_t)MPAD * NPAD * 2);        // 64.1 MB
    unsigned char* m8     = (unsigned char*)alloc((size_t)N_NODES * NPAD); // 32 MB
    bf16* B1t    = (bf16*)alloc((size_t)NPAD * K1PAD * 2);
    bf16* B2t    = (bf16*)alloc((size_t)NPAD * K2PAD * 2);
    int*   adj      = (int*)alloc((size_t)N_EDGES * 4);
    int*   row_st   = (int*)alloc((size_t)N_NODES * 4);
    int*   cursor   = (int*)alloc((size_t)N_NODES * 4);
    int*   deg_in   = (int*)alloc((size_t)N_NODES * 4);
    int*   deg_out  = (int*)alloc((size_t)N_NODES * 4);
    float* inv_in   = (float*)alloc((size_t)N_NODES * 4);
    float* inv_out  = (float*)alloc((size_t)N_NODES * 4);
    const int NB = (N_NODES + 255) / 256;
    int*   bsum     = (int*)alloc((size_t)NB * 4);
    int*   boff     = (int*)alloc((size_t)NB * 4);
    float* pooled   = (float*)alloc((size_t)N_GRAPHS * 2 * 4);
    int*   gcount   = (int*)alloc((size_t)N_GRAPHS * 4);
    float* b1p      = (float*)alloc((size_t)NPAD * 4);
    float* b2p      = (float*)alloc((size_t)NPAD * 4);
    float* wfcp     = (float*)alloc((size_t)NPAD * 2 * 4);

    hipMemsetAsync(deg_in, 0, (size_t)N_NODES * 4, stream);
    hipMemsetAsync(deg_out, 0, (size_t)N_NODES * 4, stream);
    hipMemsetAsync(pooled, 0, (size_t)N_GRAPHS * 2 * 4, stream);
    hipMemsetAsync(gcount, 0, (size_t)N_GRAPHS * 4, stream);

    // graph preprocessing
    count_deg<<<(N_EDGES + 255) / 256, 256, 0, stream>>>(src, dst, deg_out, deg_in);
    block_sum<<<NB, 256, 0, stream>>>(deg_in, bsum);
    scan_serial<<<1, 64, 0, stream>>>(bsum, boff, NB);
    node_offsets<<<NB, 256, 0, stream>>>(deg_in, deg_out, boff, row_st, cursor, inv_in, inv_out);
    fill_csr<<<(N_EDGES + 255) / 256, 256, 0, stream>>>(src, dst, cursor, adj);

    // weight conversions + padded small tensors
    conv_bt<<<(NPAD * K1PAD + 255) / 256, 256, 0, stream>>>(W1, B1t, D_IN, D_H, K1PAD);
    conv_bt<<<(NPAD * K2PAD + 255) / 256, 256, 0, stream>>>(W2, B2t, D_H, D_H, K2PAD);
    prep_small<<<3, 256, 0, stream>>>(b1, b2, Wfc, b1p, b2p, wfcp);

    // layer 1 (reg-staged fp32 A, fp8 m output)
    gemm_rs<10, true><<<MPAD / 128, 512, 0, stream>>>(x, nullptr, B1t, inv_out, m8, N_NODES);
    aggregate_fp8<<<(N_NODES * 64 + 255) / 256, 256, 0, stream>>>(m8, row_st, deg_in, adj, inv_in, b1p, h_bf);
    // layer 2 (reg-staged bf16 A)
    gemm_rs<5, false><<<MPAD / 128, 512, 0, stream>>>(nullptr, h_bf, B2t, inv_out, m8, N_NODES);
    // fused layer-2 aggregate + fc + softmax + pooling
    agg2_fc_pool<<<(N_NODES * 64 + 255) / 256, 256, 0, stream>>>(m8, row_st, deg_in, adj, inv_in, b2p,
                                                                 wfcp, bfc, gid, pooled, gcount);
    finalize<<<(N_GRAPHS * 2 + 255) / 256, 256, 0, stream>>>(pooled, gcount, (float*)d_out);
}

// Round 8
// 664.924 us; speedup vs baseline: 1.3548x; 1.0298x over previous
//
#include <hip/hip_runtime.h>
#include <hip/hip_bf16.h>
#include <hip/hip_fp8.h>

#define N_NODES 100000
#define N_EDGES 1600000
#define N_GRAPHS 2000
#define D_IN 600
#define D_H 300
#define D_OUT 2

#define NPAD 320        // padded hidden width (multiple of 64)
#define K1PAD 640       // padded K for layer-1 GEMM
#define K2PAD 320       // padded K for layer-2 GEMM
#define MPAD 100096     // 782 * 128

typedef __bf16 bf16;
typedef __bf16 bf16x8 __attribute__((ext_vector_type(8)));
typedef float f32x4 __attribute__((ext_vector_type(4)));
typedef float f32x2 __attribute__((ext_vector_type(2)));

__device__ __forceinline__ unsigned char ff8(float f) {
    __hip_fp8_e4m3 t(f); return (unsigned char)t.__x;
}

// ---------------- degree counting ----------------
__global__ __launch_bounds__(256) void count_deg(const int* __restrict__ src,
                                                 const int* __restrict__ dst,
                                                 int* __restrict__ deg_out,
                                                 int* __restrict__ deg_in) {
    int e = blockIdx.x * blockDim.x + threadIdx.x;
    if (e < N_EDGES) {
        atomicAdd(&deg_out[src[e]], 1);
        atomicAdd(&deg_in[dst[e]], 1);
    }
}

// ---------------- per-block sums of deg_in ----------------
__global__ __launch_bounds__(256) void block_sum(const int* __restrict__ deg_in,
                                                 int* __restrict__ bsum) {
    __shared__ int s[256];
    int i = blockIdx.x * 256 + threadIdx.x;
    s[threadIdx.x] = (i < N_NODES) ? deg_in[i] : 0;
    __syncthreads();
    for (int off = 128; off; off >>= 1) {
        if (threadIdx.x < off) s[threadIdx.x] += s[threadIdx.x + off];
        __syncthreads();
    }
    if (threadIdx.x == 0) bsum[blockIdx.x] = s[0];
}

// ---------------- serial scan over block sums (tiny) ----------------
__global__ void scan_serial(const int* __restrict__ bsum, int* __restrict__ boff, int nb) {
    if (threadIdx.x == 0 && blockIdx.x == 0) {
        int run = 0;
        for (int i = 0; i < nb; ++i) { boff[i] = run; run += bsum[i]; }
    }
}

// ---------------- per-node CSR offsets + inv-sqrt degrees ----------------
__global__ __launch_bounds__(256) void node_offsets(const int* __restrict__ deg_in,
                                                    const int* __restrict__ deg_out,
                                                    const int* __restrict__ boff,
                                                    int* __restrict__ row_start,
                                                    int* __restrict__ cursor,
                                                    float* __restrict__ inv_in,
                                                    float* __restrict__ inv_out) {
    __shared__ int s[256];
    int i = blockIdx.x * 256 + threadIdx.x;
    int d = (i < N_NODES) ? deg_in[i] : 0;
    s[threadIdx.x] = d;
    __syncthreads();
    for (int off = 1; off < 256; off <<= 1) {
        int v = 0;
        if (threadIdx.x >= off) v = s[threadIdx.x - off];
        __syncthreads();
        if (threadIdx.x >= off) s[threadIdx.x] += v;
        __syncthreads();
    }
    if (i < N_NODES) {
        int excl = s[threadIdx.x] - d;
        int rs = boff[blockIdx.x] + excl;
        row_start[i] = rs;
        cursor[i] = rs;
        int di = deg_in[i];
        int dout = deg_out[i];
        inv_in[i]  = (di   > 0) ? rsqrtf((float)di)   : 0.0f;
        inv_out[i] = (dout > 0) ? rsqrtf((float)dout) : 0.0f;
    }
}

// ---------------- fill CSR adjacency (incoming edges, store src) ----------------
__global__ __launch_bounds__(256) void fill_csr(const int* __restrict__ src,
                                                const int* __restrict__ dst,
                                                int* __restrict__ cursor,
                                                int* __restrict__ adj) {
    int e = blockIdx.x * blockDim.x + threadIdx.x;
    if (e < N_EDGES) {
        int pos = atomicAdd(&cursor[dst[e]], 1);
        adj[pos] = src[e];
    }
}

// ---------------- W [K][N] fp32 -> Bt [NPAD][Kpad] bf16 (transpose + zero pad) ----------------
__global__ __launch_bounds__(256) void conv_bt(const float* __restrict__ W, bf16* __restrict__ Bt,
                                               int K, int N, int Kpad) {
    int idx = blockIdx.x * 256 + threadIdx.x;
    int k = idx % Kpad;
    int n = idx / Kpad;
    if (n >= NPAD) return;
    bf16 v = (bf16)0.0f;
    if (k < K && n < N) v = (bf16)W[(size_t)k * N + n];
    Bt[(size_t)n * Kpad + k] = v;
}

// ---------------- pad bias / Wfc to NPAD with zeros ----------------
__global__ __launch_bounds__(256) void prep_small(const float* __restrict__ b1,
                                                  const float* __restrict__ b2,
                                                  const float* __restrict__ Wfc,
                                                  float* __restrict__ b1p,
                                                  float* __restrict__ b2p,
                                                  float* __restrict__ wfcp) {
    int i = blockIdx.x * 256 + threadIdx.x;
    if (i < NPAD) {
        b1p[i] = (i < D_H) ? b1[i] : 0.f;
        b2p[i] = (i < D_H) ? b2[i] : 0.f;
    }
    if (i < NPAD * 2) {
        wfcp[i] = (i < D_H * 2) ? Wfc[i] : 0.f;
    }
}

// ---------------- reg-staged MFMA GEMM (T14 async-STAGE), fp8 output ----------------
template<int NK, bool AF32>
__global__ __launch_bounds__(512) void gemm_rs(const float* __restrict__ Af,
                                               const bf16* __restrict__ Ab,
                                               const bf16* __restrict__ Bt,
                                               const float* __restrict__ rowscale,
                                               unsigned char* __restrict__ C8,
                                               int M) {
    __shared__ bf16 As[128 * 64];   // 16 KB
    __shared__ bf16 Bs[320 * 64];   // 40 KB
    const int tid = threadIdx.x;
    const int lane = tid & 63;
    const int wid = tid >> 6;
    const int wr = wid >> 2;
    const int wc = wid & 3;
    const int blockRow = blockIdx.x * 128;
    const int Kpad = NK * 64;
    const size_t rowBytes = (size_t)Kpad * 2;

    f32x4 acc[4][5] = {};

    int aO[2], aRow[2], aKs[2];
    #pragma unroll
    for (int c = 0; c < 2; ++c) {
        int o = c * 8192 + tid * 16;
        int row = o >> 7;
        int slot = (o >> 4) & 7;
        aO[c] = o; aRow[c] = row; aKs[c] = (slot ^ (row & 7)) * 8;
    }
    int bO[5], bRow[5], bKs[5];
    #pragma unroll
    for (int c = 0; c < 5; ++c) {
        int o = c * 8192 + tid * 16;
        int row = o >> 7;
        int slot = (o >> 4) & 7;
        bO[c] = o; bRow[c] = row; bKs[c] = (slot ^ (row & 7)) * 8;
    }

    float4 fA[2][2];
    bf16x8 sA[2];
    bf16x8 sB[5];

    auto loadTile = [&](int t) {
        #pragma unroll
        for (int c = 0; c < 2; ++c) {
            if (AF32) {
                int gr = blockRow + aRow[c];
                int k = t * 64 + aKs[c];
                if (gr < N_NODES && k < D_IN) {
                    const float* p = Af + (size_t)gr * D_IN + k;
                    fA[c][0] = *(const float4*)p;
                    fA[c][1] = *(const float4*)(p + 4);
                } else {
                    fA[c][0] = make_float4(0.f, 0.f, 0.f, 0.f);
                    fA[c][1] = make_float4(0.f, 0.f, 0.f, 0.f);
                }
            } else {
                const char* g = (const char*)Ab + (size_t)(blockRow + aRow[c]) * rowBytes
                                + (size_t)t * 128 + aKs[c] * 2;
                sA[c] = *(const bf16x8*)g;
            }
        }
        #pragma unroll
        for (int c = 0; c < 5; ++c) {
            const char* g = (const char*)Bt + (size_t)bRow[c] * rowBytes
                            + (size_t)t * 128 + bKs[c] * 2;
            sB[c] = *(const bf16x8*)g;
        }
    };

    loadTile(0);

    for (int t = 0; t < NK; ++t) {
        __syncthreads();
        #pragma unroll
        for (int c = 0; c < 2; ++c) {
            bf16x8 v;
            if (AF32) {
                v[0] = (bf16)fA[c][0].x; v[1] = (bf16)fA[c][0].y;
                v[2] = (bf16)fA[c][0].z; v[3] = (bf16)fA[c][0].w;
                v[4] = (bf16)fA[c][1].x; v[5] = (bf16)fA[c][1].y;
                v[6] = (bf16)fA[c][1].z; v[7] = (bf16)fA[c][1].w;
            } else {
                v = sA[c];
            }
            *(bf16x8*)((char*)As + aO[c]) = v;
        }
        #pragma unroll
        for (int c = 0; c < 5; ++c)
            *(bf16x8*)((char*)Bs + bO[c]) = sB[c];
        __syncthreads();
        if (t + 1 < NK) loadTile(t + 1);
        #pragma unroll
        for (int kk = 0; kk < 2; ++kk) {
            int slot = kk * 4 + (lane >> 4);
            bf16x8 af[4], bfr[5];
            #pragma unroll
            for (int mi = 0; mi < 4; ++mi) {
                int row = wr * 64 + mi * 16 + (lane & 15);
                int addr = row * 128 + ((slot ^ (row & 7)) << 4);
                af[mi] = *(const bf16x8*)((const char*)As + addr);
            }
            #pragma unroll
            for (int ni = 0; ni < 5; ++ni) {
                int row = wc * 80 + ni * 16 + (lane & 15);
                int addr = row * 128 + ((slot ^ (row & 7)) << 4);
                bfr[ni] = *(const bf16x8*)((const char*)Bs + addr);
            }
            #pragma unroll
            for (int mi = 0; mi < 4; ++mi)
                #pragma unroll
                for (int ni = 0; ni < 5; ++ni)
                    acc[mi][ni] = __builtin_amdgcn_mfma_f32_16x16x32_bf16(af[mi], bfr[ni], acc[mi][ni], 0, 0, 0);
        }
    }
    #pragma unroll
    for (int mi = 0; mi < 4; ++mi) {
        #pragma unroll
        for (int i = 0; i < 4; ++i) {
            int gr = blockRow + wr * 64 + mi * 16 + ((lane >> 4) << 2) + i;
            if (gr >= M) continue;
            float sc = rowscale[gr];
            #pragma unroll
            for (int ni = 0; ni < 5; ++ni) {
                int gc = wc * 80 + ni * 16 + (lane & 15);
                C8[(size_t)gr * NPAD + gc] = ff8(acc[mi][ni][i] * sc);
            }
        }
    }
}

// ---------------- fp8 gather core: wave-per-node, HW byte-select converts, unroll x8 ----------
// Lane covers bytes lane*4..+3 (one dword) and 256+lane (one byte) of each gathered row.
__device__ __forceinline__ void gather_fp8(const unsigned char* __restrict__ m8,
                                           const int* __restrict__ adj,
                                           int s, int d, int lane, float acc[5]) {
    const int cb = lane * 4;
    const int c4 = 256 + lane;
    int e = 0;
    for (; e + 8 <= d; e += 8) {
        unsigned int u[8], b[8];
        #pragma unroll
        for (int j = 0; j < 8; ++j) {
            const unsigned char* r = m8 + (size_t)adj[s + e + j] * NPAD;
            u[j] = *(const unsigned int*)(r + cb);
            b[j] = r[c4];
        }
        #pragma unroll
        for (int j = 0; j < 8; ++j) {
            f32x2 lo = __builtin_amdgcn_cvt_pk_f32_fp8(u[j], false);
            f32x2 hi = __builtin_amdgcn_cvt_pk_f32_fp8(u[j], true);
            acc[0] += lo[0]; acc[1] += lo[1]; acc[2] += hi[0]; acc[3] += hi[1];
            acc[4] += __builtin_amdgcn_cvt_f32_fp8(b[j], 0);
        }
    }
    if (e + 4 <= d) {
        unsigned int u[4], b[4];
        #pragma unroll
        for (int j = 0; j < 4; ++j) {
            const unsigned char* r = m8 + (size_t)adj[s + e + j] * NPAD;
            u[j] = *(const unsigned int*)(r + cb);
            b[j] = r[c4];
        }
        #pragma unroll
        for (int j = 0; j < 4; ++j) {
            f32x2 lo = __builtin_amdgcn_cvt_pk_f32_fp8(u[j], false);
            f32x2 hi = __builtin_amdgcn_cvt_pk_f32_fp8(u[j], true);
            acc[0] += lo[0]; acc[1] += lo[1]; acc[2] += hi[0]; acc[3] += hi[1];
            acc[4] += __builtin_amdgcn_cvt_f32_fp8(b[j], 0);
        }
        e += 4;
    }
    for (; e < d; ++e) {
        const unsigned char* r = m8 + (size_t)adj[s + e] * NPAD;
        unsigned int u = *(const unsigned int*)(r + cb);
        unsigned int b = r[c4];
        f32x2 lo = __builtin_amdgcn_cvt_pk_f32_fp8(u, false);
        f32x2 hi = __builtin_amdgcn_cvt_pk_f32_fp8(u, true);
        acc[0] += lo[0]; acc[1] += lo[1]; acc[2] += hi[0]; acc[3] += hi[1];
        acc[4] += __builtin_amdgcn_cvt_f32_fp8(b, 0);
    }
}

// ---------------- layer-1 aggregation: h = relu(inv_in * sum m[adj] + bias), fp8 in / bf16 out --
__global__ __launch_bounds__(256) void aggregate_fp8(const unsigned char* __restrict__ m8,
                                                     const int* __restrict__ row_start,
                                                     const int* __restrict__ deg_in,
                                                     const int* __restrict__ adj,
                                                     const float* __restrict__ inv_in,
                                                     const float* __restrict__ biasp,
                                                     bf16* __restrict__ h) {
    int node = (int)((blockIdx.x * (size_t)blockDim.x + threadIdx.x) >> 6);
    int lane = threadIdx.x & 63;
    if (node >= N_NODES) return;
    int s = row_start[node];
    int d = deg_in[node];
    float acc[5] = {};
    gather_fp8(m8, adj, s, d, lane, acc);
    float sc = inv_in[node];
    int cA = lane * 4;
    int c4 = 256 + lane;
    float4 bq = *(const float4*)(biasp + cA);
    bf16* out = h + (size_t)node * NPAD;
    __bf16 o4[4];
    o4[0] = (bf16)fmaxf(acc[0] * sc + bq.x, 0.f);
    o4[1] = (bf16)fmaxf(acc[1] * sc + bq.y, 0.f);
    o4[2] = (bf16)fmaxf(acc[2] * sc + bq.z, 0.f);
    o4[3] = (bf16)fmaxf(acc[3] * sc + bq.w, 0.f);
    *(float2*)(out + cA) = *(float2*)o4;
    out[c4] = (bf16)fmaxf(acc[4] * sc + biasp[c4], 0.f);
}

// ---------------- fused layer-2 aggregation + fc + softmax + pooling (fp8 in) ----------------
__global__ __launch_bounds__(256) void agg2_fc_pool(const unsigned char* __restrict__ m8,
                                                    const int* __restrict__ row_start,
                                                    const int* __restrict__ deg_in,
                                                    const int* __restrict__ adj,
                                                    const float* __restrict__ inv_in,
                                                    const float* __restrict__ biasp,
                                                    const float* __restrict__ wfcp,
                                                    const float* __restrict__ bfc,
                                                    const int* __restrict__ gid,
                                                    float* __restrict__ pooled,
                                                    int* __restrict__ gcount) {
    int node = (int)((blockIdx.x * (size_t)blockDim.x + threadIdx.x) >> 6);
    int lane = threadIdx.x & 63;
    if (node >= N_NODES) return;
    int s = row_start[node];
    int d = deg_in[node];
    float acc[5] = {};
    gather_fp8(m8, adj, s, d, lane, acc);
    float sc = inv_in[node];
    int cA = lane * 4;
    int c4 = 256 + lane;
    float4 bq = *(const float4*)(biasp + cA);
    float h0 = fmaxf(acc[0] * sc + bq.x, 0.f);
    float h1 = fmaxf(acc[1] * sc + bq.y, 0.f);
    float h2 = fmaxf(acc[2] * sc + bq.z, 0.f);
    float h3 = fmaxf(acc[3] * sc + bq.w, 0.f);
    float h4 = fmaxf(acc[4] * sc + biasp[c4], 0.f);
    float4 wA0 = *(const float4*)(wfcp + cA * 2);
    float4 wA1 = *(const float4*)(wfcp + cA * 2 + 4);
    float z0 = h0 * wA0.x + h1 * wA0.z + h2 * wA1.x + h3 * wA1.z;
    float z1 = h0 * wA0.y + h1 * wA0.w + h2 * wA1.y + h3 * wA1.w;
    z0 += h4 * wfcp[c4 * 2];
    z1 += h4 * wfcp[c4 * 2 + 1];
    for (int off = 32; off; off >>= 1) {
        z0 += __shfl_down(z0, off);
        z1 += __shfl_down(z1, off);
    }
    if (lane == 0) {
        float s0 = z0 + bfc[0], s1 = z1 + bfc[1];
        float mx = fmaxf(s0, s1);
        float e0 = __expf(s0 - mx), e1 = __expf(s1 - mx);
        float inv = 1.f / (e0 + e1);
        int g = gid[node];
        atomicAdd(&pooled[g * 2 + 0], e0 * inv);
        atomicAdd(&pooled[g * 2 + 1], e1 * inv);
        atomicAdd(&gcount[g], 1);
    }
}

// ---------------- finalize: divide by counts ----------------
__global__ __launch_bounds__(256) void finalize(const float* __restrict__ pooled,
                                                const int* __restrict__ gcount,
                                                float* __restrict__ out) {
    int i = blockIdx.x * blockDim.x + threadIdx.x;
    if (i < N_GRAPHS * 2) {
        int g = i >> 1;
        float c = (float)max(gcount[g], 1);
        out[i] = pooled[i] / c;
    }
}

extern "C" void kernel_launch(void* const* d_in, const int* in_sizes, int n_in,
                              void* d_out, int out_size, void* d_ws, size_t ws_size,
                              hipStream_t stream) {
    const float* x   = (const float*)d_in[0];
    const float* W1  = (const float*)d_in[1];
    const float* b1  = (const float*)d_in[2];
    const float* W2  = (const float*)d_in[3];
    const float* b2  = (const float*)d_in[4];
    const float* Wfc = (const float*)d_in[5];
    const float* bfc = (const float*)d_in[6];
    const int* src   = (const int*)d_in[7];
    const int* dst   = (const int*)d_in[8];
    const int* gid   = (const int*)d_in[9];

    char* ws = (char*)d_ws;
    size_t off = 0;
    auto alloc = [&](size_t bytes) -> void* {
        void* p = ws + off;
        off = (off + bytes + 255) & ~(size_t)255;
        return p;
    };
    bf16* h_bf            = (bf16*)alloc((size_t)MPAD * NPAD * 2);        // 64.1 MB
    unsigned char* m8     = (unsigned char*)alloc((size_t)N_NODES * NPAD); // 32 MB
    bf16* B1t    = (bf16*)alloc((size_t)NPAD * K1PAD * 2);
    bf16* B2t    = (bf16*)alloc((size_t)NPAD * K2PAD * 2);
    int*   adj      = (int*)alloc((size_t)N_EDGES * 4);
    int*   row_st   = (int*)alloc((size_t)N_NODES * 4);
    int*   cursor   = (int*)alloc((size_t)N_NODES * 4);
    int*   deg_in   = (int*)alloc((size_t)N_NODES * 4);
    int*   deg_out  = (int*)alloc((size_t)N_NODES * 4);
    float* inv_in   = (float*)alloc((size_t)N_NODES * 4);
    float* inv_out  = (float*)alloc((size_t)N_NODES * 4);
    const int NB = (N_NODES + 255) / 256;
    int*   bsum     = (int*)alloc((size_t)NB * 4);
    int*   boff     = (int*)alloc((size_t)NB * 4);
    float* pooled   = (float*)alloc((size_t)N_GRAPHS * 2 * 4);
    int*   gcount   = (int*)alloc((size_t)N_GRAPHS * 4);
    float* b1p      = (float*)alloc((size_t)NPAD * 4);
    float* b2p      = (float*)alloc((size_t)NPAD * 4);
    float* wfcp     = (float*)alloc((size_t)NPAD * 2 * 4);

    hipMemsetAsync(deg_in, 0, (size_t)N_NODES * 4, stream);
    hipMemsetAsync(deg_out, 0, (size_t)N_NODES * 4, stream);
    hipMemsetAsync(pooled, 0, (size_t)N_GRAPHS * 2 * 4, stream);
    hipMemsetAsync(gcount, 0, (size_t)N_GRAPHS * 4, stream);

    // graph preprocessing
    count_deg<<<(N_EDGES + 255) / 256, 256, 0, stream>>>(src, dst, deg_out, deg_in);
    block_sum<<<NB, 256, 0, stream>>>(deg_in, bsum);
    scan_serial<<<1, 64, 0, stream>>>(bsum, boff, NB);
    node_offsets<<<NB, 256, 0, stream>>>(deg_in, deg_out, boff, row_st, cursor, inv_in, inv_out);
    fill_csr<<<(N_EDGES + 255) / 256, 256, 0, stream>>>(src, dst, cursor, adj);

    // weight conversions + padded small tensors
    conv_bt<<<(NPAD * K1PAD + 255) / 256, 256, 0, stream>>>(W1, B1t, D_IN, D_H, K1PAD);
    conv_bt<<<(NPAD * K2PAD + 255) / 256, 256, 0, stream>>>(W2, B2t, D_H, D_H, K2PAD);
    prep_small<<<3, 256, 0, stream>>>(b1, b2, Wfc, b1p, b2p, wfcp);

    // layer 1 (reg-staged fp32 A, fp8 m output)
    gemm_rs<10, true><<<MPAD / 128, 512, 0, stream>>>(x, nullptr, B1t, inv_out, m8, N_NODES);
    aggregate_fp8<<<(N_NODES * 64 + 255) / 256, 256, 0, stream>>>(m8, row_st, deg_in, adj, inv_in, b1p, h_bf);
    // layer 2 (reg-staged bf16 A)
    gemm_rs<5, false><<<MPAD / 128, 512, 0, stream>>>(nullptr, h_bf, B2t, inv_out, m8, N_NODES);
    // fused layer-2 aggregate + fc + softmax + pooling
    agg2_fc_pool<<<(N_NODES * 64 + 255) / 256, 256, 0, stream>>>(m8, row_st, deg_in, adj, inv_in, b2p,
                                                                 wfcp, bfc, gid, pooled, gcount);
    finalize<<<(N_GRAPHS * 2 + 255) / 256, 256, 0, stream>>>(pooled, gcount, (float*)d_out);
}